// Round 5
// baseline (75.690 us; speedup 1.0000x reference)
//
#include <hip/hip_runtime.h>

// out[b, t, c] = data[(index[b] + t) % cycle_len][c]
// B=2048, L=720, C=64 (fp32). 377 MB pure write stream.
//
// R5 = R4's global grid-stride store order (the one change that helped:
// 76->67us) + LDS-resident table AND index. Rationale: the 43 KB table does
// NOT fit the 32 KB L1, so R4's per-element table read thrashed L1 and put
// 377 MB of read traffic + latency on L2 alongside the write stream. With
// both reads served from LDS, the VMEM pipe carries ONLY stores -- memory
// behavior identical to rocclr fillBuffer (7.0 TB/s on this chip).
// LDS = 43+8.2 KB -> 3 blocks/CU; grid 768 = exactly 3/CU, all resident.

using f4 = __attribute__((ext_vector_type(4))) float;

constexpr int CCH   = 64;         // channels
constexpr int C4    = CCH / 4;    // float4 per row = 16
constexpr int BLOCK = 256;
constexpr unsigned GRIDB = 768;   // 3 blocks/CU exactly (51.2 KB LDS each)

// Fast path: all divisors compile-time. ROWF4 = L*C4, CYC = cycle_len.
template <unsigned ROWF4, unsigned CYC, unsigned NB, unsigned ITERS>
__global__ __launch_bounds__(BLOCK) void rc_stride_lds(
    const int* __restrict__ index,
    const f4*  __restrict__ data4,   // [CYC][C4]
    f4*        __restrict__ out4)    // flat [B*L*C4]
{
    __shared__ f4  sdat[CYC * C4];   // 168*16*16B = 43008 B
    __shared__ int sidx[NB];         // 2048*4    =  8192 B

    const int tid = threadIdx.x;

    // Stage table + index (coalesced; one-time ~51 KB per block).
    #pragma unroll
    for (unsigned i = tid; i < CYC * C4; i += BLOCK)
        sdat[i] = data4[i];
    const int4* idx4 = (const int4*)index;
    #pragma unroll
    for (unsigned i = tid; i < NB / 4; i += BLOCK)
        ((int4*)sidx)[i] = idx4[i];
    __syncthreads();

    const unsigned G = GRIDB * BLOCK;            // 196608 threads
    unsigned p = blockIdx.x * BLOCK + tid;
    #pragma unroll 8
    for (unsigned i = 0; i < ITERS; ++i, p += G) {
        unsigned b   = p / ROWF4;                // magic mul (const divisor)
        unsigned q   = p - b * ROWF4;
        unsigned t   = q >> 4;
        unsigned c4  = q & (C4 - 1);
        unsigned row = ((unsigned)sidx[b] + t) % CYC;    // magic mul
        out4[p] = sdat[row * C4 + c4];           // DS read; store is only VMEM
    }
}

// Generic fallback (R1-style, correct for any shape).
__global__ __launch_bounds__(BLOCK) void rc_generic(
    const int* __restrict__ index,
    const f4*  __restrict__ data4,
    f4*        __restrict__ out4,
    int L, int cycle_len)
{
    const int tid = threadIdx.x;
    const int b   = blockIdx.x;
    const int idx = index[b];
    f4* outb = out4 + (size_t)b * (size_t)L * C4;
    const int n  = L * C4;
    const int t0 = tid >> 4;
    const int c4 = tid & (C4 - 1);
    int row = (idx + t0) % cycle_len;
    const int rstep = (BLOCK / C4) % cycle_len;
    for (int p = tid; p < n; p += BLOCK) {
        outb[p] = data4[row * C4 + c4];
        row += rstep;
        if (row >= cycle_len) row -= cycle_len;
    }
}

extern "C" void kernel_launch(void* const* d_in, const int* in_sizes, int n_in,
                              void* d_out, int out_size, void* d_ws, size_t ws_size,
                              hipStream_t stream) {
    // setup_inputs order: index [B] int32, length scalar (derived), data fp32.
    const int*   index = (const int*)d_in[0];
    const float* data  = (const float*)d_in[2];

    const int B         = in_sizes[0];
    const int cycle_len = in_sizes[2] / CCH;      // 168
    const int L         = out_size / (B * CCH);   // 720

    if (B == 2048 && L == 720 && cycle_len == 168) {
        // total f4 = 2048*720*16 = 23,592,960 = (768*256) * 120 exactly
        rc_stride_lds<720 * C4, 168, 2048, 120><<<GRIDB, BLOCK, 0, stream>>>(
            index, (const f4*)data, (f4*)d_out);
    } else {
        rc_generic<<<B, BLOCK, 0, stream>>>(
            index, (const f4*)data, (f4*)d_out, L, cycle_len);
    }
}

// Round 6
// 68.392 us; speedup vs baseline: 1.1067x; 1.1067x over previous
//
#include <hip/hip_runtime.h>

// out[b, t, c] = data[(index[b] + t) % cycle_len][c]
// B=2048, L=720, C=64 (fp32). 377 MB pure write stream.
//
// R6 = R4 (global grid-stride store order, the proven win: 76->67us) with
// ONE change: nontemporal stores. Theory: the 377 MB write stream
// write-allocates through the 32 MB L2, (a) evicting the hot 43 KB table
// so L1-miss reads fall through to L3/HBM, and (b) stealing L2 bank BW from
// the read stream. NT marks the streamed lines evict-first. R2's NT test
// was confounded by the bad block-per-b store order; this is the clean
// retest on the good order.

using f4 = __attribute__((ext_vector_type(4))) float;

constexpr int CCH   = 64;         // channels
constexpr int C4    = CCH / 4;    // float4 per row = 16
constexpr int BLOCK = 256;
constexpr unsigned GRIDB = 1024;  // 4 blocks/CU, 4 MB moving window

// Fast path: all divisors compile-time.
template <unsigned ROWF4, unsigned CYC, unsigned ITERS>
__global__ __launch_bounds__(BLOCK) void rc_stride(
    const int* __restrict__ index,
    const f4*  __restrict__ data4,   // [CYC][C4]
    f4*        __restrict__ out4)    // flat [B*L*C4]
{
    const unsigned G = GRIDB * BLOCK;            // 262144 threads
    unsigned p = blockIdx.x * BLOCK + threadIdx.x;
    #pragma unroll 4
    for (unsigned i = 0; i < ITERS; ++i, p += G) {
        unsigned b   = p / ROWF4;                // magic mul
        unsigned q   = p - b * ROWF4;
        unsigned t   = q >> 4;
        unsigned c4  = q & (C4 - 1);
        unsigned row = ((unsigned)index[b] + t) % CYC;   // magic mul
        f4 v = data4[row * C4 + c4];             // L1/L2-hit (43 KB table)
        __builtin_nontemporal_store(v, &out4[p]);
    }
}

// Generic fallback (R1-style, correct for any shape).
__global__ __launch_bounds__(BLOCK) void rc_generic(
    const int* __restrict__ index,
    const f4*  __restrict__ data4,
    f4*        __restrict__ out4,
    int L, int cycle_len)
{
    const int tid = threadIdx.x;
    const int b   = blockIdx.x;
    const int idx = index[b];
    f4* outb = out4 + (size_t)b * (size_t)L * C4;
    const int n  = L * C4;
    const int t0 = tid >> 4;
    const int c4 = tid & (C4 - 1);
    int row = (idx + t0) % cycle_len;
    const int rstep = (BLOCK / C4) % cycle_len;
    for (int p = tid; p < n; p += BLOCK) {
        outb[p] = data4[row * C4 + c4];
        row += rstep;
        if (row >= cycle_len) row -= cycle_len;
    }
}

extern "C" void kernel_launch(void* const* d_in, const int* in_sizes, int n_in,
                              void* d_out, int out_size, void* d_ws, size_t ws_size,
                              hipStream_t stream) {
    // setup_inputs order: index [B] int32, length scalar (derived), data fp32.
    const int*   index = (const int*)d_in[0];
    const float* data  = (const float*)d_in[2];

    const int B         = in_sizes[0];
    const int cycle_len = in_sizes[2] / CCH;      // 168
    const int L         = out_size / (B * CCH);   // 720

    if (B == 2048 && L == 720 && cycle_len == 168) {
        // total f4 = 2048*720*16 = 23,592,960 = (1024*256) * 90 exactly
        rc_stride<720 * C4, 168, 90><<<GRIDB, BLOCK, 0, stream>>>(
            index, (const f4*)data, (f4*)d_out);
    } else {
        rc_generic<<<B, BLOCK, 0, stream>>>(
            index, (const f4*)data, (f4*)d_out, L, cycle_len);
    }
}